// Round 6
// baseline (29.163 us; speedup 1.0000x reference)
//
#include <hip/hip_runtime.h>

#define SCALE 0.0625f

constexpr int HF = 64, WF = 64, CF = 256, BF = 8;
constexpr int P = 7, S = 4;
constexpr int BINS = P * P;                 // 49
constexpr int NROI = 256;
constexpr int NBIN_TOT = NROI * BINS;       // 12544
constexpr int POOL_BLOCKS = NBIN_TOT / 4;   // 3136
constexpr int CHUNK = POOL_BLOCKS / 8;      // 392 (XCD swizzle)
constexpr int TBLK = 8192;                  // transpose blocks in fused kernel
constexpr int SETUP_BLK = NBIN_TOT / 256;   // 49 setup blocks
constexpr size_t XT_FLOATS = (size_t)BF * CF * HF * WF;      // 2^23
constexpr size_t PAR_FLOATS = (size_t)NBIN_TOT * 16;         // 16 dwords/bin

// ---------------------------------------------------------------------------
// Kernel 1 (fused): blocks [0,8192) transpose (B,C,HW)->(B,HW,C);
// blocks [8192,8241) precompute per-bin separable weights (1 thread = 1 bin).
// ---------------------------------------------------------------------------
__global__ __launch_bounds__(256) void fused_setup(const float* __restrict__ in,
                                                   const float* __restrict__ rois,
                                                   const float* __restrict__ offset,
                                                   float* __restrict__ xt,
                                                   float* __restrict__ params) {
    __shared__ float tile[32][33];
    if (blockIdx.x < TBLK) {
        const int f   = blockIdx.x;
        const int hw0 = (f & 127) << 5;           // 128 tiles along HW
        const int c0  = ((f >> 7) & 7) << 5;      // 8 tiles along C
        const int b   = f >> 10;                  // 8 batches
        const int tx  = threadIdx.x & 31;
        const int ty  = threadIdx.x >> 5;

        const float* src = in + ((size_t)b * CF + c0) * (HF * WF) + hw0;
        #pragma unroll
        for (int i = 0; i < 32; i += 8)
            tile[ty + i][tx] = src[(size_t)(ty + i) * (HF * WF) + tx];
        __syncthreads();

        float* dst = xt + ((size_t)b * (HF * WF) + hw0) * CF + c0;
        #pragma unroll
        for (int i = 0; i < 32; i += 8)
            dst[(size_t)(ty + i) * CF + tx] = tile[tx][ty + i];
        return;
    }

    // ---- per-bin parameter computation: thread t = global bin id ----
    const int t = ((int)blockIdx.x - TBLK) * 256 + (int)threadIdx.x;  // 0..12543
    const int n   = t / BINS;
    const int bin = t - n * BINS;
    const int ph  = bin / 7;
    const int pw  = bin - ph * 7;

    const float* r = rois + n * 5;
    const int   batch  = (int)r[0];
    const float roi_sw = rintf(r[1]) * SCALE - 0.5f;   // rintf == jnp.round (half-even)
    const float roi_sh = rintf(r[2]) * SCALE - 0.5f;
    const float roi_w  = fmaxf((rintf(r[3]) + 1.0f) * SCALE - 0.5f - roi_sw, 0.1f);
    const float roi_h  = fmaxf((rintf(r[4]) + 1.0f) * SCALE - 0.5f - roi_sh, 0.1f);
    const float bin_w  = roi_w / 7.0f;
    const float bin_h  = roi_h / 7.0f;
    const float sub_w  = bin_w * 0.25f;
    const float sub_h  = bin_h * 0.25f;

    const float tx = offset[n * 98 + bin] * 0.1f;
    const float ty = offset[n * 98 + 49 + bin] * 0.1f;
    const float wstart = (float)pw * bin_w + roi_sw + tx * roi_w;
    const float hstart = (float)ph * bin_h + roi_sh + ty * roi_h;

    // separable axis weights (proven in R3/R4: sample spread -> <=4 cells/axis)
    float WX0 = 0.f, WX1 = 0.f, WX2 = 0.f, WX3 = 0.f, cw = 0.f;
    const int xbase = (int)fminf(fmaxf(wstart, 0.f), 63.f);
    #pragma unroll
    for (int i = 0; i < 4; ++i) {
        const float p  = wstart + (float)i * sub_w;
        const float vf = (p >= -0.5f && p <= 63.5f) ? 1.f : 0.f;
        cw += vf;
        const float pc = fminf(fmaxf(p, 0.f), 63.f);
        const float fx = floorf(pc);
        const float dx = pc - fx;
        const int   j  = (int)fx - xbase;
        const float lo = vf * (1.f - dx);
        const float hi = vf * dx;
        if (j == 0)      { WX0 += lo; WX1 += hi; }
        else if (j == 1) { WX1 += lo; WX2 += hi; }
        else if (j == 2) { WX2 += lo; WX3 += hi; }
        else             { WX3 += lo; }
    }
    float WY0 = 0.f, WY1 = 0.f, WY2 = 0.f, WY3 = 0.f, chh = 0.f;
    const int ybase = (int)fminf(fmaxf(hstart, 0.f), 63.f);
    #pragma unroll
    for (int i = 0; i < 4; ++i) {
        const float p  = hstart + (float)i * sub_h;
        const float vf = (p >= -0.5f && p <= 63.5f) ? 1.f : 0.f;
        chh += vf;
        const float pc = fminf(fmaxf(p, 0.f), 63.f);
        const float fy = floorf(pc);
        const float dy = pc - fy;
        const int   j  = (int)fy - ybase;
        const float lo = vf * (1.f - dy);
        const float hi = vf * dy;
        if (j == 0)      { WY0 += lo; WY1 += hi; }
        else if (j == 1) { WY1 += lo; WY2 += hi; }
        else if (j == 2) { WY2 += lo; WY3 += hi; }
        else             { WY3 += lo; }
    }

    const float cf  = cw * chh;
    const float inv = (cf > 0.f) ? (1.0f / cf) : 0.0f;

    float4* pp = (float4*)(params + ((size_t)t << 4));
    pp[0] = make_float4(WX0, WX1, WX2, WX3);
    pp[1] = make_float4(WY0, WY1, WY2, WY3);
    pp[2] = make_float4(inv, __int_as_float(batch),
                        __int_as_float(xbase), __int_as_float(ybase));
}

// ---------------------------------------------------------------------------
// Kernel 2: gather-only pool. Wave per bin (lane = 4-ch float4), 4 bins/block.
// Params broadcast-loaded; stream is ~120 instrs: clamps + <=16 gathers + FMA.
// ---------------------------------------------------------------------------
__global__ __launch_bounds__(256) void dcn_pool_gather(const float* __restrict__ xt,
                                                       const float* __restrict__ params,
                                                       float* __restrict__ out) {
    __shared__ float stage[4][260];
    const int lane = threadIdx.x & 63;
    const int wv   = threadIdx.x >> 6;
    int bid = blockIdx.x;
    bid = (bid & 7) * CHUNK + (bid >> 3);          // bijective XCD swizzle
    const int g = (bid << 2) + wv;                 // global bin id

    const float4* pp = (const float4*)(params + ((size_t)g << 4));
    const float4 WX = pp[0];
    const float4 WY = pp[1];
    const float4 M  = pp[2];
    const float inv   = M.x;
    const int   batch = __float_as_int(M.y);
    const int   xbase = __float_as_int(M.z);
    const int   ybase = __float_as_int(M.w);

    const float* bp = xt + ((size_t)batch << 20) + (lane << 2);  // batch stride 2^20 floats
    const int xi0 = xbase << 8;
    const int xi1 = min(xbase + 1, 63) << 8;
    const int xi2 = min(xbase + 2, 63) << 8;
    const int xi3 = min(xbase + 3, 63) << 8;
    const bool c3 = (WX.w != 0.f);

    float a0 = 0.f, a1 = 0.f, a2 = 0.f, a3 = 0.f;

#define DCN_ROW(WYv, cy)                                                             \
    if (WYv != 0.f) {                                                                \
        const float* rp = bp + ((size_t)min(ybase + cy, 63) << 14);                  \
        const float4 v0 = *(const float4*)(rp + xi0);                                \
        const float4 v1 = *(const float4*)(rp + xi1);                                \
        const float4 v2 = *(const float4*)(rp + xi2);                                \
        const float w0 = WYv * WX.x, w1 = WYv * WX.y, w2 = WYv * WX.z;               \
        a0 = fmaf(w0, v0.x, a0); a1 = fmaf(w0, v0.y, a1);                            \
        a2 = fmaf(w0, v0.z, a2); a3 = fmaf(w0, v0.w, a3);                            \
        a0 = fmaf(w1, v1.x, a0); a1 = fmaf(w1, v1.y, a1);                            \
        a2 = fmaf(w1, v1.z, a2); a3 = fmaf(w1, v1.w, a3);                            \
        a0 = fmaf(w2, v2.x, a0); a1 = fmaf(w2, v2.y, a1);                            \
        a2 = fmaf(w2, v2.z, a2); a3 = fmaf(w2, v2.w, a3);                            \
        if (c3) {                                                                    \
            const float4 v3 = *(const float4*)(rp + xi3);                            \
            const float w3 = WYv * WX.w;                                             \
            a0 = fmaf(w3, v3.x, a0); a1 = fmaf(w3, v3.y, a1);                        \
            a2 = fmaf(w3, v3.z, a2); a3 = fmaf(w3, v3.w, a3);                        \
        }                                                                            \
    }

    DCN_ROW(WY.x, 0)
    DCN_ROW(WY.y, 1)
    DCN_ROW(WY.z, 2)
    DCN_ROW(WY.w, 3)
#undef DCN_ROW

    ((float4*)stage[wv])[lane] = make_float4(a0 * inv, a1 * inv, a2 * inv, a3 * inv);
    __syncthreads();

    const int base_g = bid << 2;
    #pragma unroll
    for (int k = 0; k < 4; ++k) {
        const int idx = (k << 8) + threadIdx.x;
        const int c   = idx >> 2;
        const int bs  = idx & 3;
        const int gg  = base_g + bs;
        const int nn  = gg / BINS;
        const int bb2 = gg - nn * BINS;
        out[(size_t)nn * (CF * BINS) + c * BINS + bb2] = stage[bs][c];
    }
}

// ---------------------------------------------------------------------------
// Fallback: direct (B,C,H,W) gather (slow, used only if ws too small).
// ---------------------------------------------------------------------------
__global__ __launch_bounds__(256) void dcn_pool_fallback(const float* __restrict__ x,
                                                         const float* __restrict__ rois,
                                                         const float* __restrict__ offset,
                                                         float* __restrict__ out) {
    const int n   = blockIdx.x / BINS;
    const int bin = blockIdx.x % BINS;
    const int ph  = bin / P;
    const int pw  = bin % P;
    const int c   = threadIdx.x;

    const float* r = rois + n * 5;
    const int   batch  = (int)r[0];
    const float roi_sw = rintf(r[1]) * SCALE - 0.5f;
    const float roi_sh = rintf(r[2]) * SCALE - 0.5f;
    const float roi_w  = fmaxf((rintf(r[3]) + 1.0f) * SCALE - 0.5f - roi_sw, 0.1f);
    const float roi_h  = fmaxf((rintf(r[4]) + 1.0f) * SCALE - 0.5f - roi_sh, 0.1f);
    const float bin_w  = roi_w / 7.0f;
    const float bin_h  = roi_h / 7.0f;
    const float sub_w  = bin_w * 0.25f;
    const float sub_h  = bin_h * 0.25f;

    const float tx = offset[n * 98 + ph * 7 + pw] * 0.1f;
    const float ty = offset[n * 98 + 49 + ph * 7 + pw] * 0.1f;
    const float wstart = (float)pw * bin_w + roi_sw + tx * roi_w;
    const float hstart = (float)ph * bin_h + roi_sh + ty * roi_h;

    float sum = 0.0f;
    int   cnt = 0;
    for (int ih = 0; ih < S; ++ih) {
        for (int iw = 0; iw < S; ++iw) {
            const float wpos = wstart + (float)iw * sub_w;
            const float hpos = hstart + (float)ih * sub_h;
            if (wpos >= -0.5f && wpos <= (float)WF - 0.5f &&
                hpos >= -0.5f && hpos <= (float)HF - 0.5f) {
                const float wc_ = fminf(fmaxf(wpos, 0.0f), (float)(WF - 1));
                const float hc_ = fminf(fmaxf(hpos, 0.0f), (float)(HF - 1));
                const float fx = floorf(wc_);
                const float fy = floorf(hc_);
                const int x0 = (int)fx, x1i = (int)ceilf(wc_);
                const int y0 = (int)fy, y1i = (int)ceilf(hc_);
                const float dx = wc_ - fx, dy = hc_ - fy;
                const float* bbp = x + ((size_t)batch * CF + c) * (HF * WF);
                sum += (1.0f - dx) * (1.0f - dy) * bbp[y0 * WF + x0]
                     + dx * (1.0f - dy) * bbp[y0 * WF + x1i]
                     + (1.0f - dx) * dy * bbp[y1i * WF + x0]
                     + dx * dy * bbp[y1i * WF + x1i];
                ++cnt;
            }
        }
    }
    out[((size_t)n * CF + c) * BINS + bin] = (cnt > 0) ? (sum / (float)cnt) : 0.0f;
}

extern "C" void kernel_launch(void* const* d_in, const int* in_sizes, int n_in,
                              void* d_out, int out_size, void* d_ws, size_t ws_size,
                              hipStream_t stream) {
    const float* x      = (const float*)d_in[0];
    const float* rois   = (const float*)d_in[1];
    const float* offset = (const float*)d_in[2];
    float*       out    = (float*)d_out;

    const int N = in_sizes[1] / 5;
    const size_t need = (XT_FLOATS + PAR_FLOATS) * sizeof(float);

    if (ws_size >= need && N == NROI) {
        float* xt     = (float*)d_ws;
        float* params = xt + XT_FLOATS;
        fused_setup<<<TBLK + SETUP_BLK, 256, 0, stream>>>(x, rois, offset, xt, params);
        dcn_pool_gather<<<POOL_BLOCKS, 256, 0, stream>>>(xt, params, out);
    } else {
        dcn_pool_fallback<<<N * BINS, 256, 0, stream>>>(x, rois, offset, out);
    }
}

// Round 7
// 25.491 us; speedup vs baseline: 1.1441x; 1.1441x over previous
//
#include <hip/hip_runtime.h>
#include <hip/hip_fp16.h>

#define SCALE 0.0625f

constexpr int HF = 64, WF = 64, CF = 256, BF = 8;
constexpr int P = 7, S = 4;
constexpr int BINS = P * P;                 // 49
constexpr int NROI = 256;
constexpr int NBIN_TOT = NROI * BINS;       // 12544
constexpr int POOL_BLOCKS = NBIN_TOT / 4;   // 3136
constexpr int CHUNK = POOL_BLOCKS / 8;      // 392 (XCD swizzle)
constexpr int TBLK = 2048;                  // 64x64 transpose tiles: 64*4*8
constexpr int SETUP_BLK = NBIN_TOT / 256;   // 49 setup blocks
constexpr size_t XT_HALFS  = (size_t)BF * CF * HF * WF;      // 2^23 halves = 16.7 MB
constexpr size_t PAR_FLOATS = (size_t)NBIN_TOT * 16;         // 16 dwords/bin

// ---------------------------------------------------------------------------
// Kernel 1 (fused): blocks [0,2048) transpose (B,C,HW) f32 -> (B,HW,C) fp16
// with 64x64 tiles (256B/wave loads, 128B-run half2 stores);
// blocks [2048,2097) precompute per-bin separable weights (1 thread = 1 bin).
// ---------------------------------------------------------------------------
__global__ __launch_bounds__(256) void fused_setup(const float* __restrict__ in,
                                                   const float* __restrict__ rois,
                                                   const float* __restrict__ offset,
                                                   __half* __restrict__ xt,
                                                   float* __restrict__ params) {
    __shared__ float tile[64][65];             // [c][hw], pad 65: 2-way on read (free)
    if (blockIdx.x < TBLK) {
        const int f   = blockIdx.x;
        const int hw0 = (f & 63) << 6;         // 64 tiles along HW
        const int c0  = ((f >> 6) & 3) << 6;   // 4 tiles along C
        const int b   = f >> 8;                // 8 batches
        const int tx  = threadIdx.x & 63;      // hw within tile
        const int ty  = threadIdx.x >> 6;      // c base 0..3

        const float* src = in + ((size_t)(b * CF + c0 + ty)) * (HF * WF) + hw0 + tx;
        #pragma unroll
        for (int i = 0; i < 64; i += 4)
            tile[ty + i][tx] = src[(size_t)i * (HF * WF)];
        __syncthreads();

        // write: 64 hw rows x 32 half2 (=64 c, 128B contiguous per row)
        __half* dst = xt + ((size_t)b * (HF * WF) + hw0) * CF + c0;
        const int cp  = threadIdx.x & 31;      // c-pair
        const int hwl = threadIdx.x >> 5;      // 0..7
        #pragma unroll
        for (int i = 0; i < 64; i += 8) {
            const int hw = hwl + i;
            const __half2 v = __floats2half2_rn(tile[2 * cp][hw], tile[2 * cp + 1][hw]);
            *(__half2*)(dst + (size_t)hw * CF + 2 * cp) = v;
        }
        return;
    }

    // ---- per-bin parameter computation: thread t = global bin id ----
    const int t = ((int)blockIdx.x - TBLK) * 256 + (int)threadIdx.x;  // 0..12543
    const int n   = t / BINS;
    const int bin = t - n * BINS;
    const int ph  = bin / 7;
    const int pw  = bin - ph * 7;

    const float* r = rois + n * 5;
    const int   batch  = (int)r[0];
    const float roi_sw = rintf(r[1]) * SCALE - 0.5f;   // rintf == jnp.round (half-even)
    const float roi_sh = rintf(r[2]) * SCALE - 0.5f;
    const float roi_w  = fmaxf((rintf(r[3]) + 1.0f) * SCALE - 0.5f - roi_sw, 0.1f);
    const float roi_h  = fmaxf((rintf(r[4]) + 1.0f) * SCALE - 0.5f - roi_sh, 0.1f);
    const float bin_w  = roi_w / 7.0f;
    const float bin_h  = roi_h / 7.0f;
    const float sub_w  = bin_w * 0.25f;
    const float sub_h  = bin_h * 0.25f;

    const float tx = offset[n * 98 + bin] * 0.1f;
    const float ty = offset[n * 98 + 49 + bin] * 0.1f;
    const float wstart = (float)pw * bin_w + roi_sw + tx * roi_w;
    const float hstart = (float)ph * bin_h + roi_sh + ty * roi_h;

    // separable axis weights (proven R3-R5: sample spread -> <=4 cells/axis)
    float WX0 = 0.f, WX1 = 0.f, WX2 = 0.f, WX3 = 0.f, cw = 0.f;
    const int xbase = (int)fminf(fmaxf(wstart, 0.f), 63.f);
    #pragma unroll
    for (int i = 0; i < 4; ++i) {
        const float p  = wstart + (float)i * sub_w;
        const float vf = (p >= -0.5f && p <= 63.5f) ? 1.f : 0.f;
        cw += vf;
        const float pc = fminf(fmaxf(p, 0.f), 63.f);
        const float fx = floorf(pc);
        const float dx = pc - fx;
        const int   j  = (int)fx - xbase;
        const float lo = vf * (1.f - dx);
        const float hi = vf * dx;
        if (j == 0)      { WX0 += lo; WX1 += hi; }
        else if (j == 1) { WX1 += lo; WX2 += hi; }
        else if (j == 2) { WX2 += lo; WX3 += hi; }
        else             { WX3 += lo; }
    }
    float WY0 = 0.f, WY1 = 0.f, WY2 = 0.f, WY3 = 0.f, chh = 0.f;
    const int ybase = (int)fminf(fmaxf(hstart, 0.f), 63.f);
    #pragma unroll
    for (int i = 0; i < 4; ++i) {
        const float p  = hstart + (float)i * sub_h;
        const float vf = (p >= -0.5f && p <= 63.5f) ? 1.f : 0.f;
        chh += vf;
        const float pc = fminf(fmaxf(p, 0.f), 63.f);
        const float fy = floorf(pc);
        const float dy = pc - fy;
        const int   j  = (int)fy - ybase;
        const float lo = vf * (1.f - dy);
        const float hi = vf * dy;
        if (j == 0)      { WY0 += lo; WY1 += hi; }
        else if (j == 1) { WY1 += lo; WY2 += hi; }
        else if (j == 2) { WY2 += lo; WY3 += hi; }
        else             { WY3 += lo; }
    }

    const float cf  = cw * chh;
    const float inv = (cf > 0.f) ? (1.0f / cf) : 0.0f;

    float4* pp = (float4*)(params + ((size_t)t << 4));
    pp[0] = make_float4(WX0, WX1, WX2, WX3);
    pp[1] = make_float4(WY0, WY1, WY2, WY3);
    pp[2] = make_float4(inv, __int_as_float(batch),
                        __int_as_float(xbase), __int_as_float(ybase));
}

// ---------------------------------------------------------------------------
// Kernel 2: gather-only pool over fp16 xt. Wave per bin (lane = 4 channels,
// 8B ushort4 load -> 2x half2 cvt), 4 bins/block, params broadcast-loaded.
// ---------------------------------------------------------------------------
__global__ __launch_bounds__(256) void dcn_pool_gather(const __half* __restrict__ xt,
                                                       const float* __restrict__ params,
                                                       float* __restrict__ out) {
    __shared__ float stage[4][260];
    const int lane = threadIdx.x & 63;
    const int wv   = threadIdx.x >> 6;
    int bid = blockIdx.x;
    bid = (bid & 7) * CHUNK + (bid >> 3);          // bijective XCD swizzle
    const int g = (bid << 2) + wv;                 // global bin id

    const float4* pp = (const float4*)(params + ((size_t)g << 4));
    const float4 WX = pp[0];
    const float4 WY = pp[1];
    const float4 M  = pp[2];
    const float inv   = M.x;
    const int   batch = __float_as_int(M.y);
    const int   xbase = __float_as_int(M.z);
    const int   ybase = __float_as_int(M.w);

    const __half* bp = xt + ((size_t)batch << 20) + (lane << 2);  // batch stride 2^20 halves
    const int xi0 = xbase << 8;
    const int xi1 = min(xbase + 1, 63) << 8;
    const int xi2 = min(xbase + 2, 63) << 8;
    const int xi3 = min(xbase + 3, 63) << 8;
    const bool c3 = (WX.w != 0.f);

    float a0 = 0.f, a1 = 0.f, a2 = 0.f, a3 = 0.f;

#define DCN_CELL(wgt, xi)                                                            \
    {                                                                                \
        union { uint2 u; __half2 h[2]; } U;                                          \
        U.u = *(const uint2*)(rp + xi);                                              \
        const float2 f01 = __half22float2(U.h[0]);                                   \
        const float2 f23 = __half22float2(U.h[1]);                                   \
        a0 = fmaf(wgt, f01.x, a0); a1 = fmaf(wgt, f01.y, a1);                        \
        a2 = fmaf(wgt, f23.x, a2); a3 = fmaf(wgt, f23.y, a3);                        \
    }

#define DCN_ROW(WYv, cy)                                                             \
    if (WYv != 0.f) {                                                                \
        const __half* rp = bp + ((size_t)min(ybase + cy, 63) << 14);                 \
        DCN_CELL(WYv * WX.x, xi0)                                                    \
        DCN_CELL(WYv * WX.y, xi1)                                                    \
        DCN_CELL(WYv * WX.z, xi2)                                                    \
        if (c3) DCN_CELL(WYv * WX.w, xi3)                                            \
    }

    DCN_ROW(WY.x, 0)
    DCN_ROW(WY.y, 1)
    DCN_ROW(WY.z, 2)
    DCN_ROW(WY.w, 3)
#undef DCN_ROW
#undef DCN_CELL

    ((float4*)stage[wv])[lane] = make_float4(a0 * inv, a1 * inv, a2 * inv, a3 * inv);
    __syncthreads();

    const int base_g = bid << 2;
    #pragma unroll
    for (int k = 0; k < 4; ++k) {
        const int idx = (k << 8) + threadIdx.x;
        const int c   = idx >> 2;
        const int bs  = idx & 3;
        const int gg  = base_g + bs;
        const int nn  = gg / BINS;
        const int bb2 = gg - nn * BINS;
        out[(size_t)nn * (CF * BINS) + c * BINS + bb2] = stage[bs][c];
    }
}

// ---------------------------------------------------------------------------
// Fallback: direct (B,C,H,W) f32 gather (slow, used only if ws too small).
// ---------------------------------------------------------------------------
__global__ __launch_bounds__(256) void dcn_pool_fallback(const float* __restrict__ x,
                                                         const float* __restrict__ rois,
                                                         const float* __restrict__ offset,
                                                         float* __restrict__ out) {
    const int n   = blockIdx.x / BINS;
    const int bin = blockIdx.x % BINS;
    const int ph  = bin / P;
    const int pw  = bin % P;
    const int c   = threadIdx.x;

    const float* r = rois + n * 5;
    const int   batch  = (int)r[0];
    const float roi_sw = rintf(r[1]) * SCALE - 0.5f;
    const float roi_sh = rintf(r[2]) * SCALE - 0.5f;
    const float roi_w  = fmaxf((rintf(r[3]) + 1.0f) * SCALE - 0.5f - roi_sw, 0.1f);
    const float roi_h  = fmaxf((rintf(r[4]) + 1.0f) * SCALE - 0.5f - roi_sh, 0.1f);
    const float bin_w  = roi_w / 7.0f;
    const float bin_h  = roi_h / 7.0f;
    const float sub_w  = bin_w * 0.25f;
    const float sub_h  = bin_h * 0.25f;

    const float tx = offset[n * 98 + ph * 7 + pw] * 0.1f;
    const float ty = offset[n * 98 + 49 + ph * 7 + pw] * 0.1f;
    const float wstart = (float)pw * bin_w + roi_sw + tx * roi_w;
    const float hstart = (float)ph * bin_h + roi_sh + ty * roi_h;

    float sum = 0.0f;
    int   cnt = 0;
    for (int ih = 0; ih < S; ++ih) {
        for (int iw = 0; iw < S; ++iw) {
            const float wpos = wstart + (float)iw * sub_w;
            const float hpos = hstart + (float)ih * sub_h;
            if (wpos >= -0.5f && wpos <= (float)WF - 0.5f &&
                hpos >= -0.5f && hpos <= (float)HF - 0.5f) {
                const float wc_ = fminf(fmaxf(wpos, 0.0f), (float)(WF - 1));
                const float hc_ = fminf(fmaxf(hpos, 0.0f), (float)(HF - 1));
                const float fx = floorf(wc_);
                const float fy = floorf(hc_);
                const int x0 = (int)fx, x1i = (int)ceilf(wc_);
                const int y0 = (int)fy, y1i = (int)ceilf(hc_);
                const float dx = wc_ - fx, dy = hc_ - fy;
                const float* bbp = x + ((size_t)batch * CF + c) * (HF * WF);
                sum += (1.0f - dx) * (1.0f - dy) * bbp[y0 * WF + x0]
                     + dx * (1.0f - dy) * bbp[y0 * WF + x1i]
                     + (1.0f - dx) * dy * bbp[y1i * WF + x0]
                     + dx * dy * bbp[y1i * WF + x1i];
                ++cnt;
            }
        }
    }
    out[((size_t)n * CF + c) * BINS + bin] = (cnt > 0) ? (sum / (float)cnt) : 0.0f;
}

extern "C" void kernel_launch(void* const* d_in, const int* in_sizes, int n_in,
                              void* d_out, int out_size, void* d_ws, size_t ws_size,
                              hipStream_t stream) {
    const float* x      = (const float*)d_in[0];
    const float* rois   = (const float*)d_in[1];
    const float* offset = (const float*)d_in[2];
    float*       out    = (float*)d_out;

    const int N = in_sizes[1] / 5;
    const size_t need = XT_HALFS * sizeof(__half) + PAR_FLOATS * sizeof(float);

    if (ws_size >= need && N == NROI) {
        __half* xt    = (__half*)d_ws;
        float* params = (float*)(xt + XT_HALFS);
        fused_setup<<<TBLK + SETUP_BLK, 256, 0, stream>>>(x, rois, offset, xt, params);
        dcn_pool_gather<<<POOL_BLOCKS, 256, 0, stream>>>(xt, params, out);
    } else {
        dcn_pool_fallback<<<N * BINS, 256, 0, stream>>>(x, rois, offset, out);
    }
}

// Round 8
// 24.594 us; speedup vs baseline: 1.1858x; 1.0365x over previous
//
#include <hip/hip_runtime.h>
#include <hip/hip_fp16.h>

#define SCALE 0.0625f

constexpr int HF = 64, WF = 64, CF = 256, BF = 8;
constexpr int P = 7, S = 4;
constexpr int BINS = P * P;                 // 49
constexpr int NROI = 256;
constexpr int NBIN_TOT = NROI * BINS;       // 12544
constexpr int POOL_BLOCKS = NBIN_TOT / 4;   // 3136
constexpr int CHUNK = POOL_BLOCKS / 8;      // 392 (XCD swizzle)
constexpr int TBLK = 2048;                  // 64x64 transpose tiles: 64*4*8
constexpr int SETUP_BLK = NBIN_TOT / 256;   // 49 setup blocks
constexpr size_t XT_HALFS  = (size_t)BF * CF * HF * WF;      // 2^23 halves = 16.7 MB
constexpr size_t PAR_FLOATS = (size_t)NBIN_TOT * 16;         // 16 dwords/bin

// ---------------------------------------------------------------------------
// Kernel 1 (fused): blocks [0,2048) transpose (B,C,HW) f32 -> (B,HW,C) fp16
// with 64x64 tiles; blocks [2048,2097) precompute per-bin separable weights.
// ---------------------------------------------------------------------------
__global__ __launch_bounds__(256) void fused_setup(const float* __restrict__ in,
                                                   const float* __restrict__ rois,
                                                   const float* __restrict__ offset,
                                                   __half* __restrict__ xt,
                                                   float* __restrict__ params) {
    __shared__ float tile[64][65];
    if (blockIdx.x < TBLK) {
        const int f   = blockIdx.x;
        const int hw0 = (f & 63) << 6;         // 64 tiles along HW
        const int c0  = ((f >> 6) & 3) << 6;   // 4 tiles along C
        const int b   = f >> 8;                // 8 batches
        const int tx  = threadIdx.x & 63;      // hw within tile
        const int ty  = threadIdx.x >> 6;      // c base 0..3

        const float* src = in + ((size_t)(b * CF + c0 + ty)) * (HF * WF) + hw0 + tx;
        #pragma unroll
        for (int i = 0; i < 64; i += 4)
            tile[ty + i][tx] = src[(size_t)i * (HF * WF)];
        __syncthreads();

        __half* dst = xt + ((size_t)b * (HF * WF) + hw0) * CF + c0;
        const int cp  = threadIdx.x & 31;      // c-pair
        const int hwl = threadIdx.x >> 5;      // 0..7
        #pragma unroll
        for (int i = 0; i < 64; i += 8) {
            const int hw = hwl + i;
            const __half2 v = __floats2half2_rn(tile[2 * cp][hw], tile[2 * cp + 1][hw]);
            *(__half2*)(dst + (size_t)hw * CF + 2 * cp) = v;
        }
        return;
    }

    // ---- per-bin parameter computation: thread t = global bin id ----
    const int t = ((int)blockIdx.x - TBLK) * 256 + (int)threadIdx.x;  // 0..12543
    const int n   = t / BINS;
    const int bin = t - n * BINS;
    const int ph  = bin / 7;
    const int pw  = bin - ph * 7;

    const float* r = rois + n * 5;
    const int   batch  = (int)r[0];
    const float roi_sw = rintf(r[1]) * SCALE - 0.5f;   // rintf == jnp.round (half-even)
    const float roi_sh = rintf(r[2]) * SCALE - 0.5f;
    const float roi_w  = fmaxf((rintf(r[3]) + 1.0f) * SCALE - 0.5f - roi_sw, 0.1f);
    const float roi_h  = fmaxf((rintf(r[4]) + 1.0f) * SCALE - 0.5f - roi_sh, 0.1f);
    const float bin_w  = roi_w / 7.0f;
    const float bin_h  = roi_h / 7.0f;
    const float sub_w  = bin_w * 0.25f;
    const float sub_h  = bin_h * 0.25f;

    const float tx = offset[n * 98 + bin] * 0.1f;
    const float ty = offset[n * 98 + 49 + bin] * 0.1f;
    const float wstart = (float)pw * bin_w + roi_sw + tx * roi_w;
    const float hstart = (float)ph * bin_h + roi_sh + ty * roi_h;

    // separable axis weights (proven R3-R6: sample spread -> <=4 cells/axis)
    float WX0 = 0.f, WX1 = 0.f, WX2 = 0.f, WX3 = 0.f, cw = 0.f;
    const int xbase = (int)fminf(fmaxf(wstart, 0.f), 63.f);
    #pragma unroll
    for (int i = 0; i < 4; ++i) {
        const float p  = wstart + (float)i * sub_w;
        const float vf = (p >= -0.5f && p <= 63.5f) ? 1.f : 0.f;
        cw += vf;
        const float pc = fminf(fmaxf(p, 0.f), 63.f);
        const float fx = floorf(pc);
        const float dx = pc - fx;
        const int   j  = (int)fx - xbase;
        const float lo = vf * (1.f - dx);
        const float hi = vf * dx;
        if (j == 0)      { WX0 += lo; WX1 += hi; }
        else if (j == 1) { WX1 += lo; WX2 += hi; }
        else if (j == 2) { WX2 += lo; WX3 += hi; }
        else             { WX3 += lo; }
    }
    float WY0 = 0.f, WY1 = 0.f, WY2 = 0.f, WY3 = 0.f, chh = 0.f;
    const int ybase = (int)fminf(fmaxf(hstart, 0.f), 63.f);
    #pragma unroll
    for (int i = 0; i < 4; ++i) {
        const float p  = hstart + (float)i * sub_h;
        const float vf = (p >= -0.5f && p <= 63.5f) ? 1.f : 0.f;
        chh += vf;
        const float pc = fminf(fmaxf(p, 0.f), 63.f);
        const float fy = floorf(pc);
        const float dy = pc - fy;
        const int   j  = (int)fy - ybase;
        const float lo = vf * (1.f - dy);
        const float hi = vf * dy;
        if (j == 0)      { WY0 += lo; WY1 += hi; }
        else if (j == 1) { WY1 += lo; WY2 += hi; }
        else if (j == 2) { WY2 += lo; WY3 += hi; }
        else             { WY3 += lo; }
    }

    const float cf  = cw * chh;
    const float inv = (cf > 0.f) ? (1.0f / cf) : 0.0f;

    float4* pp = (float4*)(params + ((size_t)t << 4));
    pp[0] = make_float4(WX0, WX1, WX2, WX3);
    pp[1] = make_float4(WY0, WY1, WY2, WY3);
    pp[2] = make_float4(inv, __int_as_float(batch),
                        __int_as_float(xbase), __int_as_float(ybase));
}

// ---------------------------------------------------------------------------
// Kernel 2: gather pool, row-pair uint4 loads. Wave per bin:
// lane = (row-of-pair = lane>>5, channel-octet = lane&31, 16B fp16x8).
// One wave-instr fetches TWO cells (1KB). 8 gathers/bin (was 16).
// Cross-half reduction: 8x shfl_xor(32). 4 bins/block, LDS-staged write.
// ---------------------------------------------------------------------------
__global__ __launch_bounds__(256) void dcn_pool_gather(const __half* __restrict__ xt,
                                                       const float* __restrict__ params,
                                                       float* __restrict__ out) {
    __shared__ float stage[4][260];
    const int lane = threadIdx.x & 63;
    const int wv   = threadIdx.x >> 6;
    int bid = blockIdx.x;
    bid = (bid & 7) * CHUNK + (bid >> 3);          // bijective XCD swizzle
    const int g = (bid << 2) + wv;                 // global bin id

    const float4* pp = (const float4*)(params + ((size_t)g << 4));
    const float4 WX = pp[0];
    const float4 WY = pp[1];
    const float4 M  = pp[2];
    const float inv   = M.x;
    const int   batch = __float_as_int(M.y);
    const int   xbase = __float_as_int(M.z);
    const int   ybase = __float_as_int(M.w);

    const int half_ = lane >> 5;                   // which row of the pair
    const int oct   = lane & 31;                   // channel octet (8 ch)
    const __half* bp = xt + ((size_t)batch << 20) + (oct << 3);

    const int xi0 = xbase << 8;
    const int xi1 = min(xbase + 1, 63) << 8;
    const int xi2 = min(xbase + 2, 63) << 8;
    const int xi3 = min(xbase + 3, 63) << 8;
    const bool c3 = (WX.w != 0.f);

    float a0 = 0.f, a1 = 0.f, a2 = 0.f, a3 = 0.f;
    float a4 = 0.f, a5 = 0.f, a6 = 0.f, a7 = 0.f;

#define DCN_CELL(wgt, xi)                                                            \
    {                                                                                \
        union { uint4 u; __half2 h[4]; } U;                                          \
        U.u = *(const uint4*)(rp + xi);                                              \
        float2 f_;                                                                   \
        f_ = __half22float2(U.h[0]); a0 = fmaf(wgt, f_.x, a0); a1 = fmaf(wgt, f_.y, a1); \
        f_ = __half22float2(U.h[1]); a2 = fmaf(wgt, f_.x, a2); a3 = fmaf(wgt, f_.y, a3); \
        f_ = __half22float2(U.h[2]); a4 = fmaf(wgt, f_.x, a4); a5 = fmaf(wgt, f_.y, a5); \
        f_ = __half22float2(U.h[3]); a6 = fmaf(wgt, f_.x, a6); a7 = fmaf(wgt, f_.y, a7); \
    }

#define DCN_PAIR(wy_lo, wy_hi, cy0)                                                  \
    if (wy_lo != 0.f || wy_hi != 0.f) {                                              \
        const float wy = half_ ? (wy_hi) : (wy_lo);                                  \
        const __half* rp = bp + ((size_t)min(ybase + (cy0) + half_, 63) << 14);      \
        DCN_CELL(wy * WX.x, xi0)                                                     \
        DCN_CELL(wy * WX.y, xi1)                                                     \
        DCN_CELL(wy * WX.z, xi2)                                                     \
        if (c3) DCN_CELL(wy * WX.w, xi3)                                             \
    }

    DCN_PAIR(WY.x, WY.y, 0)
    DCN_PAIR(WY.z, WY.w, 2)
#undef DCN_PAIR
#undef DCN_CELL

    // cross-half reduction: lane l and l^32 hold the two rows of each pair
    a0 += __shfl_xor(a0, 32); a1 += __shfl_xor(a1, 32);
    a2 += __shfl_xor(a2, 32); a3 += __shfl_xor(a3, 32);
    a4 += __shfl_xor(a4, 32); a5 += __shfl_xor(a5, 32);
    a6 += __shfl_xor(a6, 32); a7 += __shfl_xor(a7, 32);

    // stage: lane<32 writes ch [8o,8o+4), lane>=32 writes ch [8o+4,8o+8)
    const float4 v = half_ ? make_float4(a4 * inv, a5 * inv, a6 * inv, a7 * inv)
                           : make_float4(a0 * inv, a1 * inv, a2 * inv, a3 * inv);
    ((float4*)stage[wv])[(oct << 1) | half_] = v;
    __syncthreads();

    const int base_g = bid << 2;
    #pragma unroll
    for (int k = 0; k < 4; ++k) {
        const int idx = (k << 8) + threadIdx.x;
        const int c   = idx >> 2;
        const int bs  = idx & 3;
        const int gg  = base_g + bs;
        const int nn  = gg / BINS;
        const int bb2 = gg - nn * BINS;
        out[(size_t)nn * (CF * BINS) + c * BINS + bb2] = stage[bs][c];
    }
}

// ---------------------------------------------------------------------------
// Fallback: direct (B,C,H,W) f32 gather (slow, used only if ws too small).
// ---------------------------------------------------------------------------
__global__ __launch_bounds__(256) void dcn_pool_fallback(const float* __restrict__ x,
                                                         const float* __restrict__ rois,
                                                         const float* __restrict__ offset,
                                                         float* __restrict__ out) {
    const int n   = blockIdx.x / BINS;
    const int bin = blockIdx.x % BINS;
    const int ph  = bin / P;
    const int pw  = bin % P;
    const int c   = threadIdx.x;

    const float* r = rois + n * 5;
    const int   batch  = (int)r[0];
    const float roi_sw = rintf(r[1]) * SCALE - 0.5f;
    const float roi_sh = rintf(r[2]) * SCALE - 0.5f;
    const float roi_w  = fmaxf((rintf(r[3]) + 1.0f) * SCALE - 0.5f - roi_sw, 0.1f);
    const float roi_h  = fmaxf((rintf(r[4]) + 1.0f) * SCALE - 0.5f - roi_sh, 0.1f);
    const float bin_w  = roi_w / 7.0f;
    const float bin_h  = roi_h / 7.0f;
    const float sub_w  = bin_w * 0.25f;
    const float sub_h  = bin_h * 0.25f;

    const float tx = offset[n * 98 + ph * 7 + pw] * 0.1f;
    const float ty = offset[n * 98 + 49 + ph * 7 + pw] * 0.1f;
    const float wstart = (float)pw * bin_w + roi_sw + tx * roi_w;
    const float hstart = (float)ph * bin_h + roi_sh + ty * roi_h;

    float sum = 0.0f;
    int   cnt = 0;
    for (int ih = 0; ih < S; ++ih) {
        for (int iw = 0; iw < S; ++iw) {
            const float wpos = wstart + (float)iw * sub_w;
            const float hpos = hstart + (float)ih * sub_h;
            if (wpos >= -0.5f && wpos <= (float)WF - 0.5f &&
                hpos >= -0.5f && hpos <= (float)HF - 0.5f) {
                const float wc_ = fminf(fmaxf(wpos, 0.0f), (float)(WF - 1));
                const float hc_ = fminf(fmaxf(hpos, 0.0f), (float)(HF - 1));
                const float fx = floorf(wc_);
                const float fy = floorf(hc_);
                const int x0 = (int)fx, x1i = (int)ceilf(wc_);
                const int y0 = (int)fy, y1i = (int)ceilf(hc_);
                const float dx = wc_ - fx, dy = hc_ - fy;
                const float* bbp = x + ((size_t)batch * CF + c) * (HF * WF);
                sum += (1.0f - dx) * (1.0f - dy) * bbp[y0 * WF + x0]
                     + dx * (1.0f - dy) * bbp[y0 * WF + x1i]
                     + (1.0f - dx) * dy * bbp[y1i * WF + x0]
                     + dx * dy * bbp[y1i * WF + x1i];
                ++cnt;
            }
        }
    }
    out[((size_t)n * CF + c) * BINS + bin] = (cnt > 0) ? (sum / (float)cnt) : 0.0f;
}

extern "C" void kernel_launch(void* const* d_in, const int* in_sizes, int n_in,
                              void* d_out, int out_size, void* d_ws, size_t ws_size,
                              hipStream_t stream) {
    const float* x      = (const float*)d_in[0];
    const float* rois   = (const float*)d_in[1];
    const float* offset = (const float*)d_in[2];
    float*       out    = (float*)d_out;

    const int N = in_sizes[1] / 5;
    const size_t need = XT_HALFS * sizeof(__half) + PAR_FLOATS * sizeof(float);

    if (ws_size >= need && N == NROI) {
        __half* xt    = (__half*)d_ws;
        float* params = (float*)(xt + XT_HALFS);
        fused_setup<<<TBLK + SETUP_BLK, 256, 0, stream>>>(x, rois, offset, xt, params);
        dcn_pool_gather<<<POOL_BLOCKS, 256, 0, stream>>>(xt, params, out);
    } else {
        dcn_pool_fallback<<<N * BINS, 256, 0, stream>>>(x, rois, offset, out);
    }
}